// Round 3
// baseline (129.153 us; speedup 1.0000x reference)
//
#include <hip/hip_runtime.h>

namespace {

typedef float v2f __attribute__((ext_vector_type(2)));

constexpr int kW = 640;
constexpr unsigned kSpan = 230400u;   // 360*640
constexpr int kB1 = 900;              // stats blocks (256 pts each)
constexpr int kB3 = 1024;             // count blocks (225 pts each)
constexpr int kPPB3 = 225;            // points per count block
constexpr int kB5 = 900;              // zc blocks (256 pts each)
constexpr unsigned kPoison = 0xAAAAAAAAu;

// ws layout (bytes)
constexpr size_t kOffMaxv    = 0;     // int, atomicMax accumulator of float bits
constexpr size_t kOffL17     = 8;     // f64 loss17
constexpr size_t kOffSel     = 16;    // u32 selkey
constexpr size_t kOffC1      = 256;   // k_stats arrival counter (poison-based)
constexpr size_t kOffC3      = 320;   // k_count arrival counter
constexpr size_t kOffC5      = 384;   // k_zc arrival counter
constexpr size_t kOffPlanes  = 512;                      // 1024 * 16 = 16384
constexpr size_t kOffSP      = 512 + 16384;              // 900 * 48 = 43200
constexpr size_t kOffZP      = kOffSP + 43200;           // 900 * 32 = 28800
constexpr size_t kOffPartial = kOffZP + 28800;           // 1024 * 256 * 4 = 1 MB
constexpr size_t kOffPts     = kOffPartial + (size_t)kB3 * 256 * 4;  // 230400*16
// total ~4.8 MB

__device__ __forceinline__ void ast64(unsigned long long* p, unsigned long long v) {
  __hip_atomic_store(p, v, __ATOMIC_RELAXED, __HIP_MEMORY_SCOPE_AGENT);
}
__device__ __forceinline__ unsigned long long ald64(const unsigned long long* p) {
  return __hip_atomic_load(p, __ATOMIC_RELAXED, __HIP_MEMORY_SCOPE_AGENT);
}
__device__ __forceinline__ void ast32(unsigned* p, unsigned v) {
  __hip_atomic_store(p, v, __ATOMIC_RELAXED, __HIP_MEMORY_SCOPE_AGENT);
}
__device__ __forceinline__ unsigned ald32(const unsigned* p) {
  return __hip_atomic_load(p, __ATOMIC_RELAXED, __HIP_MEMORY_SCOPE_AGENT);
}

__device__ __forceinline__ unsigned rotl32(unsigned v, int r) {
  return (v << r) | (v >> (32 - r));
}

// Threefry-2x32, 20 rounds, key = (0, 42)  [jax.random.key(42)]
__device__ __forceinline__ void threefry(unsigned c0, unsigned c1,
                                         unsigned& o0, unsigned& o1) {
  const unsigned ks0 = 0u, ks1 = 42u, ks2 = 0x1BD11BDAu ^ 0u ^ 42u;
  unsigned x0 = c0 + ks0, x1 = c1 + ks1;
#define TFR(r) { x0 += x1; x1 = rotl32(x1, (r)); x1 ^= x0; }
  TFR(13) TFR(15) TFR(26) TFR(6)
  x0 += ks1; x1 += ks2 + 1u;
  TFR(17) TFR(29) TFR(16) TFR(24)
  x0 += ks2; x1 += ks0 + 2u;
  TFR(13) TFR(15) TFR(26) TFR(6)
  x0 += ks0; x1 += ks1 + 3u;
  TFR(17) TFR(29) TFR(16) TFR(24)
  x0 += ks1; x1 += ks2 + 4u;
  TFR(13) TFR(15) TFR(26) TFR(6)
  x0 += ks2; x1 += ks0 + 5u;
#undef TFR
  o0 = x0; o1 = x1;
}

__device__ __forceinline__ void pix_coords(float d, int row, int col, bool& valid,
                                           float& x, float& y, float& z) {
  valid = (d > 0.0f) && (d < 65535.0f);
  float z0 = d / 1000.0f;
  float x0 = z0 * ((float)col - 334.081f) / 460.585f;
  float y0 = z0 * ((float)row - 169.808f) / 460.268f;
  x = x0 * 1000.0f;
  y = y0 * 1000.0f;
  z = z0 * 1000.0f;
  if (x == 0.0f) x = 1e-7f;
  if (y == 0.0f) y = 1e-7f;
  if (z == 0.0f) z = 1e-7f;
}

// normalized point — identical expression wherever used (bitwise mask consistency)
__device__ __forceinline__ void make_pt(float d, int row, int col, float maxv,
                                        float& x, float& y, float& z) {
  bool v; float a, b, c;
  pix_coords(d, row, col, v, a, b, c);
  x = (v ? a : 0.f) / maxv;
  y = (v ? b : 0.f) / maxv;
  z = (v ? c : 0.f) / maxv;
}

__device__ __forceinline__ float get_thresh(int ep) {
  return (float)fmax(0.025 - 0.001 * (double)ep, 0.005);
}

// ========== K1: stats partials + raw pts; DISTRIBUTED 5-role tail ==========
// roles 0..3 (4th..1st-from-last arrivals): 256 planes each (bounded <=4-poller spin)
// role 4 (last arrival, no spin): f64 global reduce + scalar losses
__global__ __launch_bounds__(256) void k_stats(const float* __restrict__ fake,
                                               const float* __restrict__ real,
                                               float* __restrict__ out,
                                               char* __restrict__ ws) {
  int* maxvBits = (int*)(ws + kOffMaxv);
  unsigned long long* loss17p = (unsigned long long*)(ws + kOffL17);
  unsigned* selkeyp = (unsigned*)(ws + kOffSel);
  unsigned* ctr = (unsigned*)(ws + kOffC1);
  float4* planes = (float4*)(ws + kOffPlanes);
  unsigned long long* sp = (unsigned long long*)(ws + kOffSP);
  float4* ptsraw = (float4*)(ws + kOffPts);

  const int b = blockIdx.x, t = threadIdx.x;
  const int lane = t & 63, wid = t >> 6;

  __shared__ double sD0[4], sD1[4], sD2[4], sD3[4];
  __shared__ int sI0[4];
  __shared__ float sF0[4];
  __shared__ unsigned sArr;
  __shared__ unsigned sMvU;

  {
    int i = b * 256 + t;
    int row = i / kW, col = i - row * kW;
    bool vr, vf; float rx, ry, rz, fx, fy, fz;
    pix_coords(real[i], row, col, vr, rx, ry, rz);
    pix_coords(fake[i], row, col, vf, fx, fy, fz);
    // raw (mask-applied) point — consumed by LATER KERNELS only => plain store
    ptsraw[i] = make_float4(vf ? fx : 0.f, vf ? fy : 0.f, vf ? fz : 0.f, 0.f);
    double dx2 = 0, dy2 = 0, dz2 = 0, dl2 = 0; int cc = 0;
    if (vr && vf) {
      float ddx = rx - fx, ddy = ry - fy, ddz = rz - fz;
      dx2 = (double)ddx * (double)ddx;
      dy2 = (double)ddy * (double)ddy;
      dz2 = (double)ddz * (double)ddz;
      double dl = log(fabs((double)rz)) - log(fabs((double)fz));
      dl2 = dl * dl;
      cc = 1;
    }
    float mx = vf ? fmaxf(fmaxf(fx, fy), fz) : 0.0f;
    for (int o = 32; o; o >>= 1) {
      dx2 += __shfl_down(dx2, o); dy2 += __shfl_down(dy2, o);
      dz2 += __shfl_down(dz2, o); dl2 += __shfl_down(dl2, o);
      cc += __shfl_down(cc, o);
      mx = fmaxf(mx, __shfl_down(mx, o));
    }
    if (lane == 0) { sD0[wid]=dx2; sD1[wid]=dy2; sD2[wid]=dz2; sD3[wid]=dl2;
                     sI0[wid]=cc; sF0[wid]=mx; }
    __syncthreads();
    if (t == 0) {
      unsigned long long* e = sp + (size_t)b * 6;   // in-kernel cross-block => agent stores
      ast64(e + 0, __double_as_longlong(sD0[0]+sD0[1]+sD0[2]+sD0[3]));
      ast64(e + 1, __double_as_longlong(sD1[0]+sD1[1]+sD1[2]+sD1[3]));
      ast64(e + 2, __double_as_longlong(sD2[0]+sD2[1]+sD2[2]+sD2[3]));
      ast64(e + 3, __double_as_longlong(sD3[0]+sD3[1]+sD3[2]+sD3[3]));
      ast64(e + 4, (unsigned long long)(sI0[0]+sI0[1]+sI0[2]+sI0[3]));
      float bm = fmaxf(fmaxf(sF0[0], sF0[1]), fmaxf(sF0[2], sF0[3]));
      // non-negative float bits as signed int: max is order-independent,
      // poison 0xAAAAAAAA is negative => any candidate wins
      atomicMax(maxvBits, (int)__float_as_uint(bm));
    }
  }
  __syncthreads();   // drains vmcnt: sp stores + atomicMax globally performed
  if (t == 0)
    sArr = __hip_atomic_fetch_add(ctr, 1u, __ATOMIC_RELAXED, __HIP_MEMORY_SCOPE_AGENT);
  __syncthreads();
  unsigned ret = sArr;
  if (ret < kPoison + (unsigned)(kB1 - 5)) return;
  int role = (int)(ret - (kPoison + (unsigned)(kB1 - 5)));   // 0..4

  if (role == 4) {
    // ---- last arrival: all sp entries + maxv RMWs complete. No spin. ----
    double gx = 0, gy = 0, gz = 0, gl = 0; int gc = 0;
    for (int r = t; r < kB1; r += 256) {
      const unsigned long long* e = sp + (size_t)r * 6;
      gx += __longlong_as_double(ald64(e + 0));
      gy += __longlong_as_double(ald64(e + 1));
      gz += __longlong_as_double(ald64(e + 2));
      gl += __longlong_as_double(ald64(e + 3));
      gc += (int)ald64(e + 4);
    }
    for (int o = 32; o; o >>= 1) {
      gx += __shfl_down(gx, o); gy += __shfl_down(gy, o);
      gz += __shfl_down(gz, o); gl += __shfl_down(gl, o);
      gc += __shfl_down(gc, o);
    }
    if (lane == 0) { sD0[wid]=gx; sD1[wid]=gy; sD2[wid]=gz; sD3[wid]=gl; sI0[wid]=gc; }
    __syncthreads();
    if (t == 0) {
      double SX = sD0[0]+sD0[1]+sD0[2]+sD0[3];
      double SY = sD1[0]+sD1[1]+sD1[2]+sD1[3];
      double SZ = sD2[0]+sD2[1]+sD2[2]+sD2[3];
      double SL = sD3[0]+sD3[1]+sD3[2]+sD3[3];
      int CN = sI0[0]+sI0[1]+sI0[2]+sI0[3];
      double cntd = (CN > 0) ? (double)CN : 1.0;
      double lossX = sqrt(SX / cntd);
      double lossY = sqrt(SY / cntd);
      double lossZ = sqrt(SZ / cntd);
      double rmse_log = 10000.0 * sqrt(SL / cntd);
      double loss17 = rmse_log * fabs(10.0 * (3.0 - exp(lossX) - exp(lossY) - exp(lossZ)));
      ast64(loss17p, __double_as_longlong(loss17));
      ast32(selkeyp, 0u);                 // atomicMax target for k_count's select
      out[0] = (float)rmse_log;
      out[1] = (float)lossX;
      out[2] = (float)lossY;
      out[3] = (float)lossZ;
      out[5] = (float)loss17;
    }
  } else {
    // ---- roles 0..3: need FINAL maxv => bounded spin (<=4 pollers, <=4 stragglers) ----
    if (t == 0) {
      while (ald32(ctr) != kPoison + (unsigned)kB1) __builtin_amdgcn_s_sleep(8);
      sMvU = ald32((const unsigned*)maxvBits);
    }
    __syncthreads();
    const float maxv = __uint_as_float(sMvU);
    int pid = role * 256 + t;              // 0..1023, one plane per thread
    if (pid < 1000) {
      float px[3], py[3], pz[3];
#pragma unroll
      for (int v = 0; v < 3; v++) {
        unsigned p = 3u * (unsigned)pid + (unsigned)v;
        unsigned o0, o1;
        threefry(p, p + 3000u, o0, o1);  // JAX randint: o1 % span
        unsigned idx = o1 % kSpan;
        int row = (int)(idx / kW), col = (int)idx - row * kW;
        make_pt(fake[idx], row, col, maxv, px[v], py[v], pz[v]);
      }
      float ax = px[1]-px[0], ay = py[1]-py[0], az = pz[1]-pz[0];
      float bx = px[2]-px[0], by = py[2]-py[0], bz = pz[2]-pz[0];
      float nx = ay*bz - az*by;
      float ny = az*bx - ax*bz;
      float nz = ax*by - ay*bx;
      float nn = sqrtf(nx*nx + ny*ny + nz*nz);
      nx /= nn; ny /= nn; nz /= nn;
      float kk = -(nx*px[1] + ny*py[1] + nz*pz[1]);
      planes[pid] = make_float4(nx, ny, nz, kk);   // consumed next kernel => plain store
    } else {
      planes[pid] = make_float4(0.f, 0.f, 0.f, 3e38f);  // dummy: never an inlier
    }
  }
}

// ================= K2: planes-in-VGPR count + 16-block select tail =================
__global__ __launch_bounds__(256) void k_count(const int* __restrict__ epoch,
                                               char* __restrict__ ws) {
  unsigned* selkeyp = (unsigned*)(ws + kOffSel);
  unsigned* ctr = (unsigned*)(ws + kOffC3);
  const float4* planes = (const float4*)(ws + kOffPlanes);
  unsigned* partial = (unsigned*)(ws + kOffPartial);
  const float4* ptsraw = (const float4*)(ws + kOffPts);

  const int b = blockIdx.x, t = threadIdx.x;
  const float th = get_thresh(*epoch);
  const float maxv = __uint_as_float(*(const unsigned*)(ws + kOffMaxv));

  __shared__ float4 sPts[kPPB3];
  __shared__ uint4 sAcc[16][16];
  __shared__ unsigned sArr;

  // stage this block's 225 points, normalized (identical expression to k_zc)
  if (t < kPPB3) {
    float4 r = ptsraw[b * kPPB3 + t];
    sPts[t] = make_float4(r.x / maxv, r.y / maxv, r.z / maxv, 0.f);
  }
  // each lane owns 4 planes in registers (pairs for pk_fma)
  float4 p0 = planes[t * 4 + 0], p1 = planes[t * 4 + 1];
  float4 p2 = planes[t * 4 + 2], p3 = planes[t * 4 + 3];
  v2f Ax = {p0.x, p1.x}, Ay = {p0.y, p1.y}, Az = {p0.z, p1.z}, Aw = {p0.w, p1.w};
  v2f Bx = {p2.x, p3.x}, By = {p2.y, p3.y}, Bz = {p2.z, p3.z}, Bw = {p2.w, p3.w};
  __syncthreads();

  int c0 = 0, c1 = 0, c2 = 0, c3 = 0;
#pragma unroll 5
  for (int s = 0; s < kPPB3; ++s) {
    float4 q = sPts[s];                    // broadcast ds_read_b128
    v2f qx = {q.x, q.x}, qy = {q.y, q.y}, qz = {q.z, q.z};
    // per-half chain == fmaf(qx, a, fmaf(qy, b, fmaf(qz, c, d))) — matches k_zc
    v2f dA = __builtin_elementwise_fma(qx, Ax,
             __builtin_elementwise_fma(qy, Ay,
             __builtin_elementwise_fma(qz, Az, Aw)));
    v2f dB = __builtin_elementwise_fma(qx, Bx,
             __builtin_elementwise_fma(qy, By,
             __builtin_elementwise_fma(qz, Bz, Bw)));
    c0 += (fabsf(dA.x) <= th) ? 1 : 0;
    c1 += (fabsf(dA.y) <= th) ? 1 : 0;
    c2 += (fabsf(dB.x) <= th) ? 1 : 0;
    c3 += (fabsf(dB.y) <= th) ? 1 : 0;
  }
  // counts <= 225 fit u8; one packed store per thread for the whole kernel
  ast32(&partial[b * 256 + t],
        (unsigned)c0 | ((unsigned)c1 << 8) | ((unsigned)c2 << 16) | ((unsigned)c3 << 24));

  __syncthreads();   // drains vmcnt
  if (t == 0)
    sArr = __hip_atomic_fetch_add(ctr, 1u, __ATOMIC_RELAXED, __HIP_MEMORY_SCOPE_AGENT);
  __syncthreads();
  unsigned ret = sArr;
  if (ret < kPoison + (unsigned)(kB3 - 16)) return;

  // ---- stage 1+2 select: last 16 arrivals each own 16 owner-threads (64 planes) ----
  int r = (int)(ret - (kPoison + (unsigned)(kB3 - 16)));   // 0..15
  if (t == 0) {
    while (ald32(ctr) != kPoison + (unsigned)kB3) __builtin_amdgcn_s_sleep(2);
  }
  __syncthreads();

  int owner = r * 16 + (t & 15);        // global owner-thread index 0..255
  int chunk = t >> 4;                   // 16 row-chunks of 64 rows
  unsigned s0 = 0, s1 = 0, s2 = 0, s3 = 0;
  for (int row = chunk * 64; row < chunk * 64 + 64; ++row) {
    unsigned v = ald32(&partial[row * 256 + owner]);
    s0 += v & 0xFFu; s1 += (v >> 8) & 0xFFu;
    s2 += (v >> 16) & 0xFFu; s3 += (v >> 24) & 0xFFu;
  }
  sAcc[t & 15][chunk] = make_uint4(s0, s1, s2, s3);
  __syncthreads();

  unsigned mykey = 0u;
  if (t < 16) {
    unsigned t0 = 0, t1 = 0, t2 = 0, t3 = 0;
    for (int j = 0; j < 16; ++j) {
      uint4 v = sAcc[t][j];
      t0 += v.x; t1 += v.y; t2 += v.z; t3 += v.w;
    }
    unsigned tot[4] = {t0, t1, t2, t3};
    int pbase = (r * 16 + t) * 4;
#pragma unroll
    for (int k = 0; k < 4; ++k) {
      int p = pbase + k;
      if (p < 1000) {
        int score = ((int)tot[k] > 5000) ? (int)tot[k] : -1;   // MIN_POINTS, strict >
        unsigned key = ((unsigned)(score + 2) << 10) | (unsigned)(1023 - p);
        mykey = key > mykey ? key : mykey;
      }
    }
  }
  for (int o = 32; o; o >>= 1) {
    unsigned other = __shfl_down(mykey, o);
    mykey = other > mykey ? other : mykey;
  }
  if (t == 0) atomicMax(selkeyp, mykey);
}

// ================= K3: zc reduction over best plane's inliers; last block finalizes =================
__global__ __launch_bounds__(256) void k_zc(const int* __restrict__ epoch,
                                            float* __restrict__ out,
                                            char* __restrict__ ws) {
  const unsigned long long* loss17p = (const unsigned long long*)(ws + kOffL17);
  unsigned* ctr = (unsigned*)(ws + kOffC5);
  const float4* planes = (const float4*)(ws + kOffPlanes);
  unsigned long long* zp = (unsigned long long*)(ws + kOffZP);
  const float4* ptsraw = (const float4*)(ws + kOffPts);

  const int b = blockIdx.x, t = threadIdx.x;
  const int lane = t & 63, wid = t >> 6;
  const float th = get_thresh(*epoch);
  const float maxv = __uint_as_float(*(const unsigned*)(ws + kOffMaxv));

  // best plane + rotation derived per block (cheap, uniform)
  unsigned selkey = *(const unsigned*)(ws + kOffSel);
  int best = 1023 - (int)(selkey & 1023u);
  float4 pl = planes[best];
  const float a = pl.x, bb = pl.y, c = pl.z, d = pl.w;
  float n2 = a * a + bb * bb + c * c;
  float cos_t = c / sqrtf(n2);
  float sin_t = sqrtf((a * a + bb * bb) / n2);
  float sab = sqrtf(a * a + bb * bb);
  float u1 = bb / sab, u2 = -a / sab;
  const float r0 = -u2 * sin_t, r1 = u1 * sin_t, r2 = cos_t, tz = d / c;

  __shared__ double sD0[4];
  __shared__ int sI0[4];
  __shared__ float sF0[4], sF1[4];
  __shared__ unsigned sArr;

  double sz = 0.0; int ic = 0; float zmx = -INFINITY, zmn = -INFINITY;  // zmn = max(-zc)
  {
    float4 rw = ptsraw[b * 256 + t];
    float qx = rw.x / maxv, qy = rw.y / maxv, qz = rw.z / maxv;
    // identical per-lane chain to k_count's pk_fma halves
    float dist = fmaf(qx, a, fmaf(qy, bb, fmaf(qz, c, d)));
    if (fabsf(dist) <= th) {
      float zc = fmaf(qx, r0, fmaf(qy, r1, (qz + tz) * r2));
      sz = (double)zc; ic = 1; zmx = zc; zmn = -zc;
    }
  }
  for (int o = 32; o; o >>= 1) {
    sz += __shfl_down(sz, o); ic += __shfl_down(ic, o);
    zmx = fmaxf(zmx, __shfl_down(zmx, o));
    zmn = fmaxf(zmn, __shfl_down(zmn, o));
  }
  if (lane == 0) { sD0[wid] = sz; sI0[wid] = ic; sF0[wid] = zmx; sF1[wid] = zmn; }
  __syncthreads();
  if (t == 0) {
    unsigned long long* e = zp + (size_t)b * 4;
    ast64(e + 0, __double_as_longlong(sD0[0]+sD0[1]+sD0[2]+sD0[3]));
    ast64(e + 1, (unsigned long long)(sI0[0]+sI0[1]+sI0[2]+sI0[3]));
    float bmx = fmaxf(fmaxf(sF0[0], sF0[1]), fmaxf(sF0[2], sF0[3]));
    float bmn = fmaxf(fmaxf(sF1[0], sF1[1]), fmaxf(sF1[2], sF1[3]));
    ast64(e + 2, (unsigned long long)__float_as_uint(bmx) |
                 ((unsigned long long)__float_as_uint(bmn) << 32));
  }
  __syncthreads();   // drains vmcnt
  if (t == 0)
    sArr = __hip_atomic_fetch_add(ctr, 1u, __ATOMIC_RELAXED, __HIP_MEMORY_SCOPE_AGENT);
  __syncthreads();
  if (sArr != kPoison + (unsigned)(kB5 - 1)) return;

  // ---- tail: final pmdg (last arrival, no spin) ----
  {
    double gs = 0.0; int gi = 0; float gmx = -INFINITY, gmn = -INFINITY;
    for (int r = t; r < kB5; r += 256) {
      const unsigned long long* e = zp + (size_t)r * 4;
      gs += __longlong_as_double(ald64(e + 0));
      gi += (int)ald64(e + 1);
      unsigned long long mm = ald64(e + 2);
      gmx = fmaxf(gmx, __uint_as_float((unsigned)(mm & 0xFFFFFFFFu)));
      gmn = fmaxf(gmn, __uint_as_float((unsigned)(mm >> 32)));
    }
    for (int o = 32; o; o >>= 1) {
      gs += __shfl_down(gs, o); gi += __shfl_down(gi, o);
      gmx = fmaxf(gmx, __shfl_down(gmx, o));
      gmn = fmaxf(gmn, __shfl_down(gmn, o));
    }
    if (lane == 0) { sD0[wid] = gs; sI0[wid] = gi; sF0[wid] = gmx; sF1[wid] = gmn; }
    __syncthreads();
    if (t == 0) {
      double S = sD0[0]+sD0[1]+sD0[2]+sD0[3];
      int IC = sI0[0]+sI0[1]+sI0[2]+sI0[3];
      float MX = fmaxf(fmaxf(sF0[0], sF0[1]), fmaxf(sF0[2], sF0[3]));
      float MN = fmaxf(fmaxf(sF1[0], sF1[1]), fmaxf(sF1[2], sF1[3]));
      double below = 0.0, above = 0.0;
      if (IC > 0) {
        double icd = (double)IC;
        double mean = S / icd;
        below = (double)MX - mean;    // sum(|zc - zmax|)/icnt  (all zc <= zmax)
        above = mean - (double)(-MN); // sum(|zc - zmin|)/icnt
      }
      if (above == 0.0) above = 1e-7;
      double pmdg = 1000.0 * (above + below);
      double loss17 = __longlong_as_double(ald64(loss17p));
      out[4] = (float)pmdg;
      out[6] = (float)(loss17 + pmdg);
    }
  }
}

}  // namespace

extern "C" void kernel_launch(void* const* d_in, const int* in_sizes, int n_in,
                              void* d_out, int out_size, void* d_ws, size_t ws_size,
                              hipStream_t stream) {
  (void)in_sizes; (void)n_in; (void)out_size; (void)ws_size;
  const float* fake = (const float*)d_in[0];
  const float* real = (const float*)d_in[1];
  const int* epoch = (const int*)d_in[2];
  float* out = (float*)d_out;
  char* ws = (char*)d_ws;

  k_stats<<<kB1, 256, 0, stream>>>(fake, real, out, ws);
  k_count<<<kB3, 256, 0, stream>>>(epoch, ws);
  k_zc<<<kB5, 256, 0, stream>>>(epoch, out, ws);
}